// Round 1
// 732.413 us; speedup vs baseline: 1.0336x; 1.0336x over previous
//
#include <hip/hip_runtime.h>
#include <math.h>

#define BATCH 32
#define T 2048
#define D 1024
#define KW 31
#define CPAD 15
#define KEXT 62      // 2*31 conv-patch columns
#define KTOT 1088    // 1024 + 64 (ext cols live in Amem/Bext tail)
#define BM 128
#define BN 128
#define BK 32
#define NSTEP (KTOT / BK)   // 34

typedef __bf16 bf16_8 __attribute__((ext_vector_type(8)));
typedef __bf16 bf16_4 __attribute__((ext_vector_type(4)));
typedef float  f32x4  __attribute__((ext_vector_type(4)));

__device__ __forceinline__ float tanh_fast(float x) {
    return 1.f - 2.f * __builtin_amdgcn_rcpf(__expf(2.f * x) + 1.f);
}

__device__ __forceinline__ void glds16(const void* gsrc, void* ldst) {
    __builtin_amdgcn_global_load_lds(
        (const __attribute__((address_space(1))) unsigned int*)gsrc,
        (__attribute__((address_space(3))) unsigned int*)ldst, 16, 0, 0);
}

// ---------------- P1: Bext[d][kk] = bf16([Wm | Wloc]) ----------------
__global__ __launch_bounds__(256) void k_prep_b(const float* __restrict__ Wm,
                                                const float* __restrict__ Wloc,
                                                __bf16* __restrict__ Bext) {
    const int idx = blockIdx.x * 256 + threadIdx.x;   // 1088 blocks
    const int d = idx / (KTOT / 4);
    const int kk = (idx % (KTOT / 4)) * 4;
    bf16_4 o;
    #pragma unroll
    for (int u = 0; u < 4; ++u) {
        const int k = kk + u;
        float val = 0.f;
        if (k < D) val = Wm[(size_t)d * D + k];
        else {
            const int j = k - D;
            if (j < KEXT) {
                const int c = (j >= KW) ? 1 : 0;
                const int kp = j - c * KW;
                val = Wloc[((size_t)d * 2 + c) * KW + kp];
            }
        }
        o[u] = (__bf16)val;
    }
    *(bf16_4*)(Bext + (size_t)d * KTOT + kk) = o;
}

// ---------------- P2a: Amem[row][0:1024] = bf16(memory) ----------------
__global__ __launch_bounds__(256) void k_prep_amem(const float* __restrict__ memory,
                                                   __bf16* __restrict__ Amem) {
    const int nvec = BATCH * T * (D / 8);
    for (int idx = blockIdx.x * 256 + threadIdx.x; idx < nvec; idx += gridDim.x * 256) {
        const int row = idx >> 7;              // b*T + t
        const int c = (idx & 127) * 8;
        const float* src = memory + (size_t)row * D + c;
        const f32x4 lo = *(const f32x4*)src;
        const f32x4 hi = *(const f32x4*)(src + 4);
        bf16_8 o;
        #pragma unroll
        for (int u = 0; u < 4; ++u) { o[u] = (__bf16)lo[u]; o[u + 4] = (__bf16)hi[u]; }
        *(bf16_8*)(Amem + (size_t)row * KTOT + c) = o;
    }
}

// ---------------- P2b: Amem[row][1024:1088] = bf16 conv patches ----------------
__global__ __launch_bounds__(256) void k_prep_aloc(const float* __restrict__ prev,
                                                   const float* __restrict__ cum,
                                                   __bf16* __restrict__ Amem) {
    const int idx = blockIdx.x * 256 + threadIdx.x;   // 4096 blocks
    const int row = idx >> 4;          // b*T + t
    const int j0 = (idx & 15) * 4;
    const int b = row >> 11;
    const int t = row & (T - 1);
    bf16_4 o;
    #pragma unroll
    for (int u = 0; u < 4; ++u) {
        const int j = j0 + u;
        float val = 0.f;
        if (j < KEXT) {
            const int c = (j >= KW) ? 1 : 0;
            const int kp = j - c * KW;
            const int ts = t + kp - CPAD;
            if (ts >= 0 && ts < T)
                val = (c ? cum : prev)[(size_t)b * T + ts];
        }
        o[u] = (__bf16)val;
    }
    *(bf16_4*)(Amem + (size_t)row * KTOT + D + j0) = o;
}

// ---------------- K1: q = query @ Wq^T ----------------
__global__ __launch_bounds__(256) void k_q(const float* __restrict__ query,
                                           const float* __restrict__ Wq,
                                           float* __restrict__ qout) {
    int b = blockIdx.y;
    int w = threadIdx.x >> 6;
    int lane = threadIdx.x & 63;
    int d = blockIdx.x * 4 + w;
    const float* qrow = query + (size_t)b * D;
    const float* wrow = Wq + (size_t)d * D;
    float s = 0.f;
    #pragma unroll
    for (int i = 0; i < D / 64; ++i) s += qrow[lane + i * 64] * wrow[lane + i * 64];
    #pragma unroll
    for (int off = 32; off > 0; off >>= 1) s += __shfl_down(s, off, 64);
    if (lane == 0) qout[(size_t)b * D + d] = s;
}

// ---------------- K2: bf16 MFMA GEMM + tanh·v epilogue ----------------
// Both operands staged via global_load_lds width=16 (A pre-converted to bf16 by
// k_prep_amem, conv-ext columns fused in). 2-deep LDS ring, 1 barrier/step,
// stage(k+1) issued before compute(k) so glds overlaps ds_read+MFMA.
__global__ __launch_bounds__(256, 4) void k_gemm_e(
    const __bf16* __restrict__ Amem, const __bf16* __restrict__ Bext,
    const float* __restrict__ qv, const float* __restrict__ vvec,
    float* __restrict__ e_part) {
    __shared__ bf16_8 As[2][512];   // 2 x 8 KB
    __shared__ bf16_8 Bs[2][512];

    const int t0 = blockIdx.x * BM;
    const int d0 = blockIdx.y * BN;
    const int b  = blockIdx.z;
    const int tid  = threadIdx.x;
    const int lane = tid & 63;
    const int w    = tid >> 6;
    const int wr   = w >> 1, wc = w & 1;
    const int q    = lane >> 4, m = lane & 15;

    f32x4 acc[4][4] = {};

    const int g0 = w, g1 = w + 4;
    const __bf16* aptr0 = Amem + ((size_t)b * T + t0 + g0 * 16 + m) * KTOT + q * 8;
    const __bf16* aptr1 = Amem + ((size_t)b * T + t0 + g1 * 16 + m) * KTOT + q * 8;
    const __bf16* bptr0 = Bext + (size_t)(d0 + g0 * 16 + m) * KTOT + q * 8;
    const __bf16* bptr1 = Bext + (size_t)(d0 + g1 * 16 + m) * KTOT + q * 8;

    // prologue: stage K-step 0 into buf 0
    glds16(aptr0, &As[0][g0 * 64]);
    glds16(aptr1, &As[0][g1 * 64]);
    glds16(bptr0, &Bs[0][g0 * 64]);
    glds16(bptr1, &Bs[0][g1 * 64]);
    __syncthreads();

    for (int k = 0; k < NSTEP; ++k) {
        const int p = k & 1;
        const int kn = k + 1;
        if (kn < NSTEP) {                 // stage next step first: overlaps compute
            const int kk = kn * BK;
            glds16(aptr0 + kk, &As[p ^ 1][g0 * 64]);
            glds16(aptr1 + kk, &As[p ^ 1][g1 * 64]);
            glds16(bptr0 + kk, &Bs[p ^ 1][g0 * 64]);
            glds16(bptr1 + kk, &Bs[p ^ 1][g1 * 64]);
        }
        bf16_8 bfr[4];
        #pragma unroll
        for (int j = 0; j < 4; ++j) bfr[j] = Bs[p][(wc * 4 + j) * 64 + lane];
        #pragma unroll
        for (int i = 0; i < 4; ++i) {
            const bf16_8 af = As[p][(wr * 4 + i) * 64 + lane];
            #pragma unroll
            for (int j = 0; j < 4; ++j)
                acc[i][j] = __builtin_amdgcn_mfma_f32_16x16x32_bf16(af, bfr[j], acc[i][j], 0, 0, 0);
        }
        __syncthreads();                  // drains glds(k+1) + everyone done reading buf p
    }

    // epilogue: e(t) += sum_d tanh(acc + q[d]) * v[d]
    float qreg[4], vreg[4];
    #pragma unroll
    for (int j = 0; j < 4; ++j) {
        const int d = d0 + wc * 64 + j * 16 + m;
        qreg[j] = qv[(size_t)b * D + d];
        vreg[j] = vvec[d];
    }
    const int dch = blockIdx.y * 2 + wc;
    #pragma unroll
    for (int i = 0; i < 4; ++i) {
        #pragma unroll
        for (int r = 0; r < 4; ++r) {
            float s = 0.f;
            #pragma unroll
            for (int j = 0; j < 4; ++j)
                s += tanh_fast(acc[i][j][r] + qreg[j]) * vreg[j];
            #pragma unroll
            for (int off = 8; off > 0; off >>= 1)
                s += __shfl_down(s, off, 16);
            if (m == 0) {
                const int t = t0 + wr * 64 + i * 16 + q * 4 + r;
                e_part[((size_t)b * T + t) * 16 + dch] = s;
            }
        }
    }
}

// ---------------- K3: masked softmax over T ----------------
__global__ __launch_bounds__(256) void k_softmax(const float* __restrict__ e_part,
                                                 const int* __restrict__ mask,
                                                 float* __restrict__ aout) {
    const int b = blockIdx.x;
    const int tid = threadIdx.x;
    __shared__ float red[256];
    float ev[8];
    float lmax = -INFINITY;
    #pragma unroll
    for (int i = 0; i < 8; ++i) {
        const int t = tid + i * 256;
        const float* p = e_part + ((size_t)b * T + t) * 16;
        float s = 0.f;
        #pragma unroll
        for (int c = 0; c < 16; ++c) s += p[c];
        if (mask[(size_t)b * T + t] != 0) s = -INFINITY;
        ev[i] = s;
        lmax = fmaxf(lmax, s);
    }
    red[tid] = lmax; __syncthreads();
    for (int off = 128; off > 0; off >>= 1) {
        if (tid < off) red[tid] = fmaxf(red[tid], red[tid + off]);
        __syncthreads();
    }
    const float mx = red[0]; __syncthreads();
    float lsum = 0.f;
    #pragma unroll
    for (int i = 0; i < 8; ++i) {
        const float x = expf(ev[i] - mx);
        ev[i] = x;
        lsum += x;
    }
    red[tid] = lsum; __syncthreads();
    for (int off = 128; off > 0; off >>= 1) {
        if (tid < off) red[tid] += red[tid + off];
        __syncthreads();
    }
    const float inv = 1.f / red[0];
    #pragma unroll
    for (int i = 0; i < 8; ++i)
        aout[(size_t)b * T + tid + i * 256] = ev[i] * inv;
}

// ---------------- K4: partial ctx, 64-t chunks (1024 blocks) ----------------
__global__ __launch_bounds__(256) void k_ctx_part(const float* __restrict__ memory,
                                                  const float* __restrict__ a,
                                                  float* __restrict__ ctx_part) {
    const int b = blockIdx.x;
    const int tc = blockIdx.y;       // 0..31, 64 t each
    const int d4 = threadIdx.x * 4;
    f32x4 acc = {0.f, 0.f, 0.f, 0.f};
    const float* mb = memory + ((size_t)b * T + (size_t)tc * 64) * D;
    const float* ab = a + (size_t)b * T + (size_t)tc * 64;
    #pragma unroll 4
    for (int t = 0; t < 64; ++t) {
        const float wgt = ab[t];
        const f32x4 m4 = *(const f32x4*)(mb + (size_t)t * D + d4);
        acc += wgt * m4;
    }
    *(f32x4*)(ctx_part + ((size_t)(b * 32 + tc)) * D + d4) = acc;
}

// ---------------- K5: reduce 32 ctx partials ----------------
__global__ __launch_bounds__(256) void k_ctx_red(const float* __restrict__ ctx_part,
                                                 float* __restrict__ ctx) {
    const int idx = blockIdx.x * 256 + threadIdx.x;
    const int b = idx >> 10, d = idx & 1023;
    float s = 0.f;
    #pragma unroll
    for (int tc = 0; tc < 32; ++tc) s += ctx_part[((size_t)(b * 32 + tc)) * D + d];
    ctx[idx] = s;
}

extern "C" void kernel_launch(void* const* d_in, const int* in_sizes, int n_in,
                              void* d_out, int out_size, void* d_ws, size_t ws_size,
                              hipStream_t stream) {
    const float* query  = (const float*)d_in[0];
    const float* memory = (const float*)d_in[1];
    const float* prev   = (const float*)d_in[2];
    const float* cum    = (const float*)d_in[3];
    const int*   mask   = (const int*)d_in[4];
    const float* Wq     = (const float*)d_in[5];
    const float* Wm     = (const float*)d_in[6];
    const float* Wloc   = (const float*)d_in[7];
    const float* v      = (const float*)d_in[8];

    float* out = (float*)d_out;
    float* ctx = out;               // [B, D]
    float* a   = out + BATCH * D;   // [B, T]

    char* ws = (char*)d_ws;
    float*  qv       = (float*)(ws + 0);                 // 128 KB
    float*  e_part   = (float*)(ws + 131072);            // 4 MB   [B,T,16]
    float*  ctx_part = (float*)(ws + 4325376);           // 4 MB   [B,32,D]
    __bf16* Bext     = (__bf16*)(ws + 8519680);          // 2.23 MB [1024,1088]
    __bf16* Amem     = (__bf16*)(ws + 10747904);         // 136 MB  [B*T,1088] bf16
    // total ~146.3 MB

    k_prep_b<<<KTOT * D / (256 * 4), 256, 0, stream>>>(Wm, Wloc, Bext);
    k_prep_amem<<<8192, 256, 0, stream>>>(memory, Amem);
    k_prep_aloc<<<BATCH * T * 16 / 256, 256, 0, stream>>>(prev, cum, Amem);
    k_q<<<dim3(D / 4, BATCH), 256, 0, stream>>>(query, Wq, qv);
    k_gemm_e<<<dim3(T / BM, D / BN, BATCH), 256, 0, stream>>>(Amem, Bext, qv, v, e_part);
    k_softmax<<<BATCH, 256, 0, stream>>>(e_part, mask, a);
    k_ctx_part<<<dim3(BATCH, 32), 256, 0, stream>>>(memory, a, ctx_part);
    k_ctx_red<<<(BATCH * D) / 256, 256, 0, stream>>>(ctx_part, ctx);
}

// Round 2
// 729.041 us; speedup vs baseline: 1.0384x; 1.0046x over previous
//
#include <hip/hip_runtime.h>
#include <math.h>

#define BATCH 32
#define T 2048
#define D 1024
#define KW 31
#define CPAD 15
#define KEXT 62      // 2*31 conv-patch columns
#define KTOT 1088    // 1024 + 64 (ext cols live in Amem/Bext tail)
#define BM 128
#define BN 128
#define BK 32
#define NSTEP (KTOT / BK)   // 34

typedef __bf16 bf16_8 __attribute__((ext_vector_type(8)));
typedef __bf16 bf16_4 __attribute__((ext_vector_type(4)));
typedef float  f32x4  __attribute__((ext_vector_type(4)));

__device__ __forceinline__ float tanh_fast(float x) {
    return 1.f - 2.f * __builtin_amdgcn_rcpf(__expf(2.f * x) + 1.f);
}

__device__ __forceinline__ void glds16(const void* gsrc, void* ldst) {
    __builtin_amdgcn_global_load_lds(
        (const __attribute__((address_space(1))) unsigned int*)gsrc,
        (__attribute__((address_space(3))) unsigned int*)ldst, 16, 0, 0);
}

// ---------------- P1: Bext[d][kk] = bf16([Wm | Wloc]) ----------------
__global__ __launch_bounds__(256) void k_prep_b(const float* __restrict__ Wm,
                                                const float* __restrict__ Wloc,
                                                __bf16* __restrict__ Bext) {
    const int idx = blockIdx.x * 256 + threadIdx.x;   // 1088 blocks
    const int d = idx / (KTOT / 4);
    const int kk = (idx % (KTOT / 4)) * 4;
    bf16_4 o;
    #pragma unroll
    for (int u = 0; u < 4; ++u) {
        const int k = kk + u;
        float val = 0.f;
        if (k < D) val = Wm[(size_t)d * D + k];
        else {
            const int j = k - D;
            if (j < KEXT) {
                const int c = (j >= KW) ? 1 : 0;
                const int kp = j - c * KW;
                val = Wloc[((size_t)d * 2 + c) * KW + kp];
            }
        }
        o[u] = (__bf16)val;
    }
    *(bf16_4*)(Bext + (size_t)d * KTOT + kk) = o;
}

// ---------------- P2a: Amem[row][0:1024] = bf16(memory), 16 elems/thread ----------------
__global__ __launch_bounds__(256) void k_prep_amem(const float* __restrict__ memory,
                                                   __bf16* __restrict__ Amem) {
    const int nvec = BATCH * T * (D / 16);
    for (int idx = blockIdx.x * 256 + threadIdx.x; idx < nvec; idx += gridDim.x * 256) {
        const int row = idx >> 6;              // b*T + t   (64 threads per row)
        const int c = (idx & 63) * 16;
        const float* src = memory + (size_t)row * D + c;
        const f32x4 a0 = *(const f32x4*)(src);
        const f32x4 a1 = *(const f32x4*)(src + 4);
        const f32x4 a2 = *(const f32x4*)(src + 8);
        const f32x4 a3 = *(const f32x4*)(src + 12);
        bf16_8 o0, o1;
        #pragma unroll
        for (int u = 0; u < 4; ++u) {
            o0[u] = (__bf16)a0[u]; o0[u + 4] = (__bf16)a1[u];
            o1[u] = (__bf16)a2[u]; o1[u + 4] = (__bf16)a3[u];
        }
        __bf16* dst = Amem + (size_t)row * KTOT + c;
        *(bf16_8*)(dst) = o0;
        *(bf16_8*)(dst + 8) = o1;
    }
}

// ---------------- P2b: Amem[row][1024:1088] = bf16 conv patches ----------------
__global__ __launch_bounds__(256) void k_prep_aloc(const float* __restrict__ prev,
                                                   const float* __restrict__ cum,
                                                   __bf16* __restrict__ Amem) {
    const int idx = blockIdx.x * 256 + threadIdx.x;   // 4096 blocks
    const int row = idx >> 4;          // b*T + t
    const int j0 = (idx & 15) * 4;
    const int b = row >> 11;
    const int t = row & (T - 1);
    bf16_4 o;
    #pragma unroll
    for (int u = 0; u < 4; ++u) {
        const int j = j0 + u;
        float val = 0.f;
        if (j < KEXT) {
            const int c = (j >= KW) ? 1 : 0;
            const int kp = j - c * KW;
            const int ts = t + kp - CPAD;
            if (ts >= 0 && ts < T)
                val = (c ? cum : prev)[(size_t)b * T + ts];
        }
        o[u] = (__bf16)val;
    }
    *(bf16_4*)(Amem + (size_t)row * KTOT + D + j0) = o;
}

// ---------------- K1: q = query @ Wq^T ----------------
__global__ __launch_bounds__(256) void k_q(const float* __restrict__ query,
                                           const float* __restrict__ Wq,
                                           float* __restrict__ qout) {
    int b = blockIdx.y;
    int w = threadIdx.x >> 6;
    int lane = threadIdx.x & 63;
    int d = blockIdx.x * 4 + w;
    const float* qrow = query + (size_t)b * D;
    const float* wrow = Wq + (size_t)d * D;
    float s = 0.f;
    #pragma unroll
    for (int i = 0; i < D / 64; ++i) s += qrow[lane + i * 64] * wrow[lane + i * 64];
    #pragma unroll
    for (int off = 32; off > 0; off >>= 1) s += __shfl_down(s, off, 64);
    if (lane == 0) qout[(size_t)b * D + d] = s;
}

// ---------------- K2: bf16 MFMA GEMM + tanh·v epilogue ----------------
// Counted-vmcnt pipeline (T4): A 3-deep ring (distance-2 prefetch, covers
// L3/HBM latency), B 2-deep (distance-1, Bext is L2-hot). Raw s_barrier,
// vmcnt(2) steady-state (never 0 in loop). Issue order per step:
//   [vmcnt(2); s_barrier; issue B(k+1), A(k+2); ds_read(k); MFMA(k)]
// Safety: writer of a ring slot issues post-barrier(k); last reader of that
// slot finished pre-barrier(k). vmcnt before barrier because vmcnt is
// per-wave; barrier publishes all waves' landed loads.
__global__ __launch_bounds__(256, 4) void k_gemm_e(
    const __bf16* __restrict__ Amem, const __bf16* __restrict__ Bext,
    const float* __restrict__ qv, const float* __restrict__ vvec,
    float* __restrict__ e_part) {
    __shared__ bf16_8 As[3][512];   // 3 x 8 KB
    __shared__ bf16_8 Bs[2][512];   // 2 x 8 KB   -> 40 KB total

    const int t0 = blockIdx.x * BM;
    const int d0 = blockIdx.y * BN;
    const int b  = blockIdx.z;
    const int tid  = threadIdx.x;
    const int lane = tid & 63;
    const int w    = tid >> 6;
    const int wr   = w >> 1, wc = w & 1;
    const int q    = lane >> 4, m = lane & 15;

    f32x4 acc[4][4] = {};

    const int g0 = w, g1 = w + 4;
    const __bf16* aptr0 = Amem + ((size_t)b * T + t0 + g0 * 16 + m) * KTOT + q * 8;
    const __bf16* aptr1 = Amem + ((size_t)b * T + t0 + g1 * 16 + m) * KTOT + q * 8;
    const __bf16* bptr0 = Bext + (size_t)(d0 + g0 * 16 + m) * KTOT + q * 8;
    const __bf16* bptr1 = Bext + (size_t)(d0 + g1 * 16 + m) * KTOT + q * 8;

    auto compute = [&](int pA, int pB) {
        bf16_8 bfr[4];
        #pragma unroll
        for (int j = 0; j < 4; ++j) bfr[j] = Bs[pB][(wc * 4 + j) * 64 + lane];
        #pragma unroll
        for (int i = 0; i < 4; ++i) {
            const bf16_8 af = As[pA][(wr * 4 + i) * 64 + lane];
            #pragma unroll
            for (int j = 0; j < 4; ++j)
                acc[i][j] = __builtin_amdgcn_mfma_f32_16x16x32_bf16(af, bfr[j], acc[i][j], 0, 0, 0);
        }
    };

    // prologue: A(0), B(0), A(1)  (order matters for vmcnt counting)
    glds16(aptr0,      &As[0][g0 * 64]);
    glds16(aptr1,      &As[0][g1 * 64]);
    glds16(bptr0,      &Bs[0][g0 * 64]);
    glds16(bptr1,      &Bs[0][g1 * 64]);
    glds16(aptr0 + BK, &As[1][g0 * 64]);
    glds16(aptr1 + BK, &As[1][g1 * 64]);

    #pragma unroll 1
    for (int k = 0; k < NSTEP - 1; ++k) {
        // outstanding (oldest->newest): [A(k)?], B(k), A(k+1). Need A(k),B(k).
        asm volatile("s_waitcnt vmcnt(2)" ::: "memory");
        __builtin_amdgcn_s_barrier();
        const int kb1 = k + 1;            // always < NSTEP here
        glds16(bptr0 + kb1 * BK, &Bs[kb1 & 1][g0 * 64]);
        glds16(bptr1 + kb1 * BK, &Bs[kb1 & 1][g1 * 64]);
        const int ka2 = k + 2;
        if (ka2 < NSTEP) {
            glds16(aptr0 + ka2 * BK, &As[ka2 % 3][g0 * 64]);
            glds16(aptr1 + ka2 * BK, &As[ka2 % 3][g1 * 64]);
        }
        compute(k % 3, k & 1);
    }
    asm volatile("s_waitcnt vmcnt(0)" ::: "memory");
    __builtin_amdgcn_s_barrier();
    compute((NSTEP - 1) % 3, (NSTEP - 1) & 1);

    // epilogue: e(t) += sum_d tanh(acc + q[d]) * v[d]
    float qreg[4], vreg[4];
    #pragma unroll
    for (int j = 0; j < 4; ++j) {
        const int d = d0 + wc * 64 + j * 16 + m;
        qreg[j] = qv[(size_t)b * D + d];
        vreg[j] = vvec[d];
    }
    const int dch = blockIdx.y * 2 + wc;
    #pragma unroll
    for (int i = 0; i < 4; ++i) {
        #pragma unroll
        for (int r = 0; r < 4; ++r) {
            float s = 0.f;
            #pragma unroll
            for (int j = 0; j < 4; ++j)
                s += tanh_fast(acc[i][j][r] + qreg[j]) * vreg[j];
            #pragma unroll
            for (int off = 8; off > 0; off >>= 1)
                s += __shfl_down(s, off, 16);
            if (m == 0) {
                const int t = t0 + wr * 64 + i * 16 + q * 4 + r;
                e_part[((size_t)b * T + t) * 16 + dch] = s;
            }
        }
    }
}

// ---------------- K3: masked softmax over T ----------------
__global__ __launch_bounds__(256) void k_softmax(const float* __restrict__ e_part,
                                                 const int* __restrict__ mask,
                                                 float* __restrict__ aout) {
    const int b = blockIdx.x;
    const int tid = threadIdx.x;
    __shared__ float red[256];
    float ev[8];
    float lmax = -INFINITY;
    #pragma unroll
    for (int i = 0; i < 8; ++i) {
        const int t = tid + i * 256;
        const float* p = e_part + ((size_t)b * T + t) * 16;
        float s = 0.f;
        #pragma unroll
        for (int c = 0; c < 16; ++c) s += p[c];
        if (mask[(size_t)b * T + t] != 0) s = -INFINITY;
        ev[i] = s;
        lmax = fmaxf(lmax, s);
    }
    red[tid] = lmax; __syncthreads();
    for (int off = 128; off > 0; off >>= 1) {
        if (tid < off) red[tid] = fmaxf(red[tid], red[tid + off]);
        __syncthreads();
    }
    const float mx = red[0]; __syncthreads();
    float lsum = 0.f;
    #pragma unroll
    for (int i = 0; i < 8; ++i) {
        const float x = expf(ev[i] - mx);
        ev[i] = x;
        lsum += x;
    }
    red[tid] = lsum; __syncthreads();
    for (int off = 128; off > 0; off >>= 1) {
        if (tid < off) red[tid] += red[tid + off];
        __syncthreads();
    }
    const float inv = 1.f / red[0];
    #pragma unroll
    for (int i = 0; i < 8; ++i)
        aout[(size_t)b * T + tid + i * 256] = ev[i] * inv;
}

// ---------------- K4: partial ctx, 64-t chunks (1024 blocks) ----------------
__global__ __launch_bounds__(256) void k_ctx_part(const float* __restrict__ memory,
                                                  const float* __restrict__ a,
                                                  float* __restrict__ ctx_part) {
    const int b = blockIdx.x;
    const int tc = blockIdx.y;       // 0..31, 64 t each
    const int d4 = threadIdx.x * 4;
    f32x4 acc = {0.f, 0.f, 0.f, 0.f};
    const float* mb = memory + ((size_t)b * T + (size_t)tc * 64) * D;
    const float* ab = a + (size_t)b * T + (size_t)tc * 64;
    #pragma unroll 4
    for (int t = 0; t < 64; ++t) {
        const float wgt = ab[t];
        const f32x4 m4 = *(const f32x4*)(mb + (size_t)t * D + d4);
        acc += wgt * m4;
    }
    *(f32x4*)(ctx_part + ((size_t)(b * 32 + tc)) * D + d4) = acc;
}

// ---------------- K5: reduce 32 ctx partials ----------------
__global__ __launch_bounds__(256) void k_ctx_red(const float* __restrict__ ctx_part,
                                                 float* __restrict__ ctx) {
    const int idx = blockIdx.x * 256 + threadIdx.x;
    const int b = idx >> 10, d = idx & 1023;
    float s = 0.f;
    #pragma unroll
    for (int tc = 0; tc < 32; ++tc) s += ctx_part[((size_t)(b * 32 + tc)) * D + d];
    ctx[idx] = s;
}

extern "C" void kernel_launch(void* const* d_in, const int* in_sizes, int n_in,
                              void* d_out, int out_size, void* d_ws, size_t ws_size,
                              hipStream_t stream) {
    const float* query  = (const float*)d_in[0];
    const float* memory = (const float*)d_in[1];
    const float* prev   = (const float*)d_in[2];
    const float* cum    = (const float*)d_in[3];
    const int*   mask   = (const int*)d_in[4];
    const float* Wq     = (const float*)d_in[5];
    const float* Wm     = (const float*)d_in[6];
    const float* Wloc   = (const float*)d_in[7];
    const float* v      = (const float*)d_in[8];

    float* out = (float*)d_out;
    float* ctx = out;               // [B, D]
    float* a   = out + BATCH * D;   // [B, T]

    char* ws = (char*)d_ws;
    float*  qv       = (float*)(ws + 0);                 // 128 KB
    float*  e_part   = (float*)(ws + 131072);            // 4 MB   [B,T,16]
    float*  ctx_part = (float*)(ws + 4325376);           // 4 MB   [B,32,D]
    __bf16* Bext     = (__bf16*)(ws + 8519680);          // 2.23 MB [1024,1088]
    __bf16* Amem     = (__bf16*)(ws + 10747904);         // 136 MB  [B*T,1088] bf16
    // total ~146.3 MB

    k_prep_b<<<KTOT * D / (256 * 4), 256, 0, stream>>>(Wm, Wloc, Bext);
    k_prep_amem<<<4096, 256, 0, stream>>>(memory, Amem);
    k_prep_aloc<<<BATCH * T * 16 / 256, 256, 0, stream>>>(prev, cum, Amem);
    k_q<<<dim3(D / 4, BATCH), 256, 0, stream>>>(query, Wq, qv);
    k_gemm_e<<<dim3(T / BM, D / BN, BATCH), 256, 0, stream>>>(Amem, Bext, qv, v, e_part);
    k_softmax<<<BATCH, 256, 0, stream>>>(e_part, mask, a);
    k_ctx_part<<<dim3(BATCH, 32), 256, 0, stream>>>(memory, a, ctx_part);
    k_ctx_red<<<(BATCH * D) / 256, 256, 0, stream>>>(ctx_part, ctx);
}

// Round 4
// 686.081 us; speedup vs baseline: 1.1034x; 1.0626x over previous
//
#include <hip/hip_runtime.h>
#include <math.h>

#define BATCH 32
#define T 2048
#define D 1024
#define KW 31
#define CPAD 15
#define KEXT 62      // 2*31 conv-patch columns
#define KTOT 1088    // 1024 + 64 (ext cols live in Amem/Bext tail)
#define BM 256
#define BN 256
#define KSTEP 64
#define NK (KTOT / KSTEP)   // 17

typedef __bf16 bf16_8 __attribute__((ext_vector_type(8)));
typedef __bf16 bf16_4 __attribute__((ext_vector_type(4)));
typedef float  f32x4  __attribute__((ext_vector_type(4)));

__device__ __forceinline__ float tanh_fast(float x) {
    return 1.f - 2.f * __builtin_amdgcn_rcpf(__expf(2.f * x) + 1.f);
}

__device__ __forceinline__ void glds16(const void* gsrc, void* ldst) {
    __builtin_amdgcn_global_load_lds(
        (const __attribute__((address_space(1))) unsigned int*)gsrc,
        (__attribute__((address_space(3))) unsigned int*)ldst, 16, 0, 0);
}

#define VM4 asm volatile("s_waitcnt vmcnt(4)" ::: "memory")
#define VM0 asm volatile("s_waitcnt vmcnt(0)" ::: "memory")
#define BAR __builtin_amdgcn_s_barrier()
#define PRIO1 __builtin_amdgcn_s_setprio(1)
#define PRIO0 __builtin_amdgcn_s_setprio(0)

// ---------------- P1: Bext[d][kk] = bf16([Wm | Wloc]) ----------------
__global__ __launch_bounds__(256) void k_prep_b(const float* __restrict__ Wm,
                                                const float* __restrict__ Wloc,
                                                __bf16* __restrict__ Bext) {
    const int idx = blockIdx.x * 256 + threadIdx.x;   // 1088 blocks
    const int d = idx / (KTOT / 4);
    const int kk = (idx % (KTOT / 4)) * 4;
    bf16_4 o;
    #pragma unroll
    for (int u = 0; u < 4; ++u) {
        const int k = kk + u;
        float val = 0.f;
        if (k < D) val = Wm[(size_t)d * D + k];
        else {
            const int j = k - D;
            if (j < KEXT) {
                const int c = (j >= KW) ? 1 : 0;
                const int kp = j - c * KW;
                val = Wloc[((size_t)d * 2 + c) * KW + kp];
            }
        }
        o[u] = (__bf16)val;
    }
    *(bf16_4*)(Bext + (size_t)d * KTOT + kk) = o;
}

// ---------------- P2a: Amem[row][0:1024] = bf16(memory) ----------------
__global__ __launch_bounds__(256) void k_prep_amem(const float* __restrict__ memory,
                                                   __bf16* __restrict__ Amem) {
    const int nvec = BATCH * T * (D / 16);
    for (int idx = blockIdx.x * 256 + threadIdx.x; idx < nvec; idx += gridDim.x * 256) {
        const int row = idx >> 6;              // b*T + t   (64 threads per row)
        const int c = (idx & 63) * 16;
        const float* src = memory + (size_t)row * D + c;
        const f32x4 a0 = *(const f32x4*)(src);
        const f32x4 a1 = *(const f32x4*)(src + 4);
        const f32x4 a2 = *(const f32x4*)(src + 8);
        const f32x4 a3 = *(const f32x4*)(src + 12);
        bf16_8 o0, o1;
        #pragma unroll
        for (int u = 0; u < 4; ++u) {
            o0[u] = (__bf16)a0[u]; o0[u + 4] = (__bf16)a1[u];
            o1[u] = (__bf16)a2[u]; o1[u + 4] = (__bf16)a3[u];
        }
        __bf16* dst = Amem + (size_t)row * KTOT + c;
        *(bf16_8*)(dst) = o0;
        *(bf16_8*)(dst + 8) = o1;
    }
}

// ---------------- P2b: Amem[row][1024:1088] = bf16 conv patches ----------------
__global__ __launch_bounds__(256) void k_prep_aloc(const float* __restrict__ prev,
                                                   const float* __restrict__ cum,
                                                   __bf16* __restrict__ Amem) {
    const int idx = blockIdx.x * 256 + threadIdx.x;   // 4096 blocks
    const int row = idx >> 4;          // b*T + t
    const int j0 = (idx & 15) * 4;
    const int b = row >> 11;
    const int t = row & (T - 1);
    bf16_4 o;
    #pragma unroll
    for (int u = 0; u < 4; ++u) {
        const int j = j0 + u;
        float val = 0.f;
        if (j < KEXT) {
            const int c = (j >= KW) ? 1 : 0;
            const int kp = j - c * KW;
            const int ts = t + kp - CPAD;
            if (ts >= 0 && ts < T)
                val = (c ? cum : prev)[(size_t)b * T + ts];
        }
        o[u] = (__bf16)val;
    }
    *(bf16_4*)(Amem + (size_t)row * KTOT + D + j0) = o;
}

// ---------------- K1: q = query @ Wq^T ----------------
__global__ __launch_bounds__(256) void k_q(const float* __restrict__ query,
                                           const float* __restrict__ Wq,
                                           float* __restrict__ qout) {
    int b = blockIdx.y;
    int w = threadIdx.x >> 6;
    int lane = threadIdx.x & 63;
    int d = blockIdx.x * 4 + w;
    const float* qrow = query + (size_t)b * D;
    const float* wrow = Wq + (size_t)d * D;
    float s = 0.f;
    #pragma unroll
    for (int i = 0; i < D / 64; ++i) s += qrow[lane + i * 64] * wrow[lane + i * 64];
    #pragma unroll
    for (int off = 32; off > 0; off >>= 1) s += __shfl_down(s, off, 64);
    if (lane == 0) qout[(size_t)b * D + d] = s;
}

// ---------------- K2: 256x256 phase-split MFMA GEMM + tanh*v epilogue ----------------
// m201-template port (T3+T4+T5): per K-tile (BK=64) 4 quadrant-phases, each
// {ds-read this phase's frags; issue 1 half-tile glds(k+1); BAR; 16 MFMA under
// setprio; counted vmcnt gate; BAR}. Gates vmcnt(4) at phase-ends 0,1,3 drain
// exactly the half needed next phase; never 0 in loop (min 4 loads in flight).
// Invariant at tile top: outstanding = {Bh1(k), Ah1(k)} = 4 loads.
// Fragment-major LDS (slot = 64 lanes x 16B): conflict-free glds + ds_read_b128.
__global__ __launch_bounds__(512, 2) void k_gemm_e(
    const __bf16* __restrict__ Amem, const __bf16* __restrict__ Bext,
    const float* __restrict__ qv, const float* __restrict__ vvec,
    float* __restrict__ e_part) {
    __shared__ bf16_8 As[2][2048];   // 2 x 32 KB  (32 slots x 64 lanes)
    __shared__ bf16_8 Bs[2][2048];   // 2 x 32 KB  -> 128 KB total

    const int t0 = blockIdx.x * BM;
    const int d0 = blockIdx.y * BN;
    const int b  = blockIdx.z;
    const int tid  = threadIdx.x;
    const int lane = tid & 63;
    const int w    = tid >> 6;     // 0..7
    const int wm   = w >> 2;       // 0..1  (row-wave)
    const int wn   = w & 3;        // 0..3  (col-wave)
    const int ml   = lane & 15;
    const int qk   = lane >> 4;

    f32x4 acc[8][4] = {};

    // staging: per STG call each wave issues 2 glds covering one half-tile
    // (16 slots). A half h: mf in {h*4..h*4+3} u {h*4+8..h*4+11};
    // B half h: nf in {h*2, h*2+1, h*2+4, h*2+5, h*2+8, h*2+9, h*2+12, h*2+13}.
    // slot = (mf*2+kf) resp (nf*2+kf), 64 lanes x 16B each.
    const __bf16* gA[2][2];
    const __bf16* gB[2][2];
    int sA[2][2], sB[2][2];
    #pragma unroll
    for (int h = 0; h < 2; ++h) {
        #pragma unroll
        for (int j = 0; j < 2; ++j) {
            const int idx = j * 8 + w;
            const int p = idx >> 1, kfa = idx & 1;
            const int mf = h * 4 + (p & 3) + (idx & 8);
            const int nf = h * 2 + (p & 1) + (p >> 1) * 4;
            gA[h][j] = Amem + ((size_t)b * T + t0 + mf * 16 + ml) * KTOT + kfa * 32 + qk * 8;
            sA[h][j] = (mf * 2 + kfa) * 64;
            gB[h][j] = Bext + (size_t)(d0 + nf * 16 + ml) * KTOT + kfa * 32 + qk * 8;
            sB[h][j] = (nf * 2 + kfa) * 64;
        }
    }

    bf16_8 areg[4][2];               // current A quadrant (overwritten at ph2)
    bf16_8 breg0[2][2], breg1[2][2]; // B halves jh=0 / jh=1

    auto STG_A = [&](int h, int kcol, bf16_8* dst) {
        glds16(gA[h][0] + kcol, dst + sA[h][0]);
        glds16(gA[h][1] + kcol, dst + sA[h][1]);
    };
    auto STG_B = [&](int h, int kcol, bf16_8* dst) {
        glds16(gB[h][0] + kcol, dst + sB[h][0]);
        glds16(gB[h][1] + kcol, dst + sB[h][1]);
    };
    auto LDA = [&](const bf16_8* buf, int ih) {
        #pragma unroll
        for (int i = 0; i < 4; ++i)
            #pragma unroll
            for (int kf = 0; kf < 2; ++kf)
                areg[i][kf] = buf[((wm * 8 + ih * 4 + i) * 2 + kf) * 64 + lane];
    };
    auto LDB = [&](bf16_8 (&dst)[2][2], const bf16_8* buf, int jh) {
        #pragma unroll
        for (int j = 0; j < 2; ++j)
            #pragma unroll
            for (int kf = 0; kf < 2; ++kf)
                dst[j][kf] = buf[((wn * 4 + jh * 2 + j) * 2 + kf) * 64 + lane];
    };
    auto QMM = [&](bf16_8 (&bb)[2][2], int ih, int jh) {
        #pragma unroll
        for (int i = 0; i < 4; ++i)
            #pragma unroll
            for (int kf = 0; kf < 2; ++kf)
                #pragma unroll
                for (int j = 0; j < 2; ++j)
                    acc[ih * 4 + i][jh * 2 + j] = __builtin_amdgcn_mfma_f32_16x16x32_bf16(
                        areg[i][kf], bb[j][kf], acc[ih * 4 + i][jh * 2 + j], 0, 0, 0);
    };

    // ---- prologue: stage tile 0, FIFO order Ah0,Bh0,Bh1,Ah1 (8 loads) ----
    STG_A(0, 0, As[0]);
    STG_B(0, 0, Bs[0]);
    STG_B(1, 0, Bs[0]);
    STG_A(1, 0, As[0]);
    VM4;                 // drains Ah0(0),Bh0(0); leaves Bh1(0),Ah1(0) in flight
    BAR;

    #pragma unroll 1
    for (int k = 0; k < NK; ++k) {
        const bf16_8* Ac = As[k & 1];
        const bf16_8* Bc = Bs[k & 1];
        bf16_8* An = As[(k + 1) & 1];
        bf16_8* Bn = Bs[(k + 1) & 1];
        const int c1 = ((k + 1 < NK) ? (k + 1) : 0) * KSTEP;   // dead-wrap tail
        // ph0: quad(0,0). reads Ah0(k),Bh0(k) [drained end of tile k-1]
        LDA(Ac, 0);
        LDB(breg0, Bc, 0);
        STG_A(0, c1, An);            // outstanding: Bh1(k),Ah1(k),Ah0(k+1) = 6
        BAR;
        PRIO1; QMM(breg0, 0, 0); PRIO0;
        VM4;                         // drains Bh1(k)  [needed ph1]
        BAR;
        // ph1: quad(0,1). reads Bh1(k)
        LDB(breg1, Bc, 1);
        STG_B(0, c1, Bn);            // outstanding: Ah1(k),Ah0(k+1),Bh0(k+1) = 6
        BAR;
        PRIO1; QMM(breg1, 0, 1); PRIO0;
        VM4;                         // drains Ah1(k)  [needed ph2]
        BAR;
        // ph2: quad(1,0). reads Ah1(k)
        LDA(Ac, 1);
        STG_B(1, c1, Bn);            // outstanding: Ah0(k+1),Bh0(k+1),Bh1(k+1) = 6
        BAR;
        PRIO1; QMM(breg0, 1, 0); PRIO0;
        BAR;                         // no gate (ph3 reads nothing)
        // ph3: quad(1,1). no reads
        STG_A(1, c1, An);            // outstanding: 8
        BAR;
        PRIO1; QMM(breg1, 1, 1); PRIO0;
        VM4;                         // drains Ah0(k+1),Bh0(k+1) [needed next ph0]
        BAR;
    }
    VM0;   // drain dead-wrap loads before epilogue / kernel exit

    // ---- epilogue: e(t) += sum_d tanh(acc + q[d]) * v[d] ----
    float qreg[4], vreg[4];
    #pragma unroll
    for (int jb = 0; jb < 4; ++jb) {
        const int d = d0 + wn * 64 + jb * 16 + ml;
        qreg[jb] = qv[(size_t)b * D + d];
        vreg[jb] = vvec[d];
    }
    const int dch = blockIdx.y * 4 + wn;
    #pragma unroll
    for (int ia = 0; ia < 8; ++ia) {
        #pragma unroll
        for (int r = 0; r < 4; ++r) {
            float s = 0.f;
            #pragma unroll
            for (int jb = 0; jb < 4; ++jb)
                s += tanh_fast(acc[ia][jb][r] + qreg[jb]) * vreg[jb];
            #pragma unroll
            for (int off = 8; off > 0; off >>= 1)
                s += __shfl_down(s, off, 16);
            if (ml == 0) {
                const int t = t0 + wm * 128 + ia * 16 + qk * 4 + r;
                e_part[((size_t)b * T + t) * 16 + dch] = s;
            }
        }
    }
}

// ---------------- K3: masked softmax over T ----------------
__global__ __launch_bounds__(256) void k_softmax(const float* __restrict__ e_part,
                                                 const int* __restrict__ mask,
                                                 float* __restrict__ aout) {
    const int b = blockIdx.x;
    const int tid = threadIdx.x;
    __shared__ float red[256];
    float ev[8];
    float lmax = -INFINITY;
    #pragma unroll
    for (int i = 0; i < 8; ++i) {
        const int t = tid + i * 256;
        const float* p = e_part + ((size_t)b * T + t) * 16;
        float s = 0.f;
        #pragma unroll
        for (int c = 0; c < 16; ++c) s += p[c];
        if (mask[(size_t)b * T + t] != 0) s = -INFINITY;
        ev[i] = s;
        lmax = fmaxf(lmax, s);
    }
    red[tid] = lmax; __syncthreads();
    for (int off = 128; off > 0; off >>= 1) {
        if (tid < off) red[tid] = fmaxf(red[tid], red[tid + off]);
        __syncthreads();
    }
    const float mx = red[0]; __syncthreads();
    float lsum = 0.f;
    #pragma unroll
    for (int i = 0; i < 8; ++i) {
        const float x = expf(ev[i] - mx);
        ev[i] = x;
        lsum += x;
    }
    red[tid] = lsum; __syncthreads();
    for (int off = 128; off > 0; off >>= 1) {
        if (tid < off) red[tid] += red[tid + off];
        __syncthreads();
    }
    const float inv = 1.f / red[0];
    #pragma unroll
    for (int i = 0; i < 8; ++i)
        aout[(size_t)b * T + tid + i * 256] = ev[i] * inv;
}

// ---------------- K4: partial ctx, 64-t chunks (1024 blocks) ----------------
__global__ __launch_bounds__(256) void k_ctx_part(const float* __restrict__ memory,
                                                  const float* __restrict__ a,
                                                  float* __restrict__ ctx_part) {
    const int b = blockIdx.x;
    const int tc = blockIdx.y;       // 0..31, 64 t each
    const int d4 = threadIdx.x * 4;
    f32x4 acc = {0.f, 0.f, 0.f, 0.f};
    const float* mb = memory + ((size_t)b * T + (size_t)tc * 64) * D;
    const float* ab = a + (size_t)b * T + (size_t)tc * 64;
    #pragma unroll 4
    for (int t = 0; t < 64; ++t) {
        const float wgt = ab[t];
        const f32x4 m4 = *(const f32x4*)(mb + (size_t)t * D + d4);
        acc += wgt * m4;
    }
    *(f32x4*)(ctx_part + ((size_t)(b * 32 + tc)) * D + d4) = acc;
}

// ---------------- K5: reduce 32 ctx partials ----------------
__global__ __launch_bounds__(256) void k_ctx_red(const float* __restrict__ ctx_part,
                                                 float* __restrict__ ctx) {
    const int idx = blockIdx.x * 256 + threadIdx.x;
    const int b = idx >> 10, d = idx & 1023;
    float s = 0.f;
    #pragma unroll
    for (int tc = 0; tc < 32; ++tc) s += ctx_part[((size_t)(b * 32 + tc)) * D + d];
    ctx[idx] = s;
}

extern "C" void kernel_launch(void* const* d_in, const int* in_sizes, int n_in,
                              void* d_out, int out_size, void* d_ws, size_t ws_size,
                              hipStream_t stream) {
    const float* query  = (const float*)d_in[0];
    const float* memory = (const float*)d_in[1];
    const float* prev   = (const float*)d_in[2];
    const float* cum    = (const float*)d_in[3];
    const int*   mask   = (const int*)d_in[4];
    const float* Wq     = (const float*)d_in[5];
    const float* Wm     = (const float*)d_in[6];
    const float* Wloc   = (const float*)d_in[7];
    const float* v      = (const float*)d_in[8];

    float* out = (float*)d_out;
    float* ctx = out;               // [B, D]
    float* a   = out + BATCH * D;   // [B, T]

    char* ws = (char*)d_ws;
    float*  qv       = (float*)(ws + 0);                 // 128 KB
    float*  e_part   = (float*)(ws + 131072);            // 4 MB   [B,T,16]
    float*  ctx_part = (float*)(ws + 4325376);           // 4 MB   [B,32,D]
    __bf16* Bext     = (__bf16*)(ws + 8519680);          // 2.23 MB [1024,1088]
    __bf16* Amem     = (__bf16*)(ws + 10747904);         // 136 MB  [B*T,1088] bf16
    // total ~146.3 MB

    k_prep_b<<<KTOT * D / (256 * 4), 256, 0, stream>>>(Wm, Wloc, Bext);
    k_prep_amem<<<4096, 256, 0, stream>>>(memory, Amem);
    k_prep_aloc<<<BATCH * T * 16 / 256, 256, 0, stream>>>(prev, cum, Amem);
    k_q<<<dim3(D / 4, BATCH), 256, 0, stream>>>(query, Wq, qv);
    k_gemm_e<<<dim3(T / BM, D / BN, BATCH), 512, 0, stream>>>(Amem, Bext, qv, v, e_part);
    k_softmax<<<BATCH, 256, 0, stream>>>(e_part, mask, a);
    k_ctx_part<<<dim3(BATCH, 32), 256, 0, stream>>>(memory, a, ctx_part);
    k_ctx_red<<<(BATCH * D) / 256, 256, 0, stream>>>(ctx_part, ctx);
}

// Round 5
// 640.965 us; speedup vs baseline: 1.1811x; 1.0704x over previous
//
#include <hip/hip_runtime.h>
#include <math.h>

#define BATCH 32
#define T 2048
#define D 1024
#define KW 31
#define CPAD 15
#define KEXT 62      // 2*31 conv-patch columns
#define KTOT 1088    // 1024 + 64 (ext cols live in Amem/Bext tail)
#define BM 256
#define BN 256
#define KSTEP 64
#define NK (KTOT / KSTEP)   // 17

typedef __bf16 bf16_8 __attribute__((ext_vector_type(8)));
typedef __bf16 bf16_4 __attribute__((ext_vector_type(4)));
typedef float  f32x4  __attribute__((ext_vector_type(4)));

__device__ __forceinline__ float tanh_fast(float x) {
    return 1.f - 2.f * __builtin_amdgcn_rcpf(__expf(2.f * x) + 1.f);
}

__device__ __forceinline__ void glds16(const void* gsrc, void* ldst) {
    __builtin_amdgcn_global_load_lds(
        (const __attribute__((address_space(1))) unsigned int*)gsrc,
        (__attribute__((address_space(3))) unsigned int*)ldst, 16, 0, 0);
}

#define VM4 asm volatile("s_waitcnt vmcnt(4)" ::: "memory")
#define VM0 asm volatile("s_waitcnt vmcnt(0)" ::: "memory")
#define BAR __builtin_amdgcn_s_barrier()
#define PRIO1 __builtin_amdgcn_s_setprio(1)
#define PRIO0 __builtin_amdgcn_s_setprio(0)

// ---------------- P: merged prep (amem | q | aloc | b) ----------------
// Block ranges (dispatch order = issue order; amem is longest so it goes
// first; q overlaps its L2-bound reads with amem's HBM streams):
//   [0,4096)        : Amem[row][0:1024] = bf16(memory)
//   [4096,12288)    : qv = query @ Wq^T
//   [12288,16384)   : Amem[row][1024:1088] = bf16 conv patches
//   [16384,17472)   : Bext = bf16([Wm | Wloc])
#define PREP_BLOCKS 17472
__global__ __launch_bounds__(256) void k_prep_all(
    const float* __restrict__ Wm, const float* __restrict__ Wloc,
    __bf16* __restrict__ Bext,
    const float* __restrict__ memory, __bf16* __restrict__ Amem,
    const float* __restrict__ prev, const float* __restrict__ cum,
    const float* __restrict__ query, const float* __restrict__ Wq,
    float* __restrict__ qout) {
    const int gb = blockIdx.x;
    if (gb < 4096) {
        // ---- Amem body: 16 fp32 -> bf16 per thread, grid-stride ----
        const int nvec = BATCH * T * (D / 16);
        for (int idx = gb * 256 + threadIdx.x; idx < nvec; idx += 4096 * 256) {
            const int row = idx >> 6;              // b*T + t  (64 threads/row)
            const int c = (idx & 63) * 16;
            const float* src = memory + (size_t)row * D + c;
            const f32x4 a0 = *(const f32x4*)(src);
            const f32x4 a1 = *(const f32x4*)(src + 4);
            const f32x4 a2 = *(const f32x4*)(src + 8);
            const f32x4 a3 = *(const f32x4*)(src + 12);
            bf16_8 o0, o1;
            #pragma unroll
            for (int u = 0; u < 4; ++u) {
                o0[u] = (__bf16)a0[u]; o0[u + 4] = (__bf16)a1[u];
                o1[u] = (__bf16)a2[u]; o1[u + 4] = (__bf16)a3[u];
            }
            __bf16* dst = Amem + (size_t)row * KTOT + c;
            *(bf16_8*)(dst) = o0;
            *(bf16_8*)(dst + 8) = o1;
        }
    } else if (gb < 12288) {
        // ---- q = query @ Wq^T ----
        const int j = gb - 4096;
        const int xb = j & 255;
        const int b = j >> 8;
        const int w = threadIdx.x >> 6;
        const int lane = threadIdx.x & 63;
        const int d = xb * 4 + w;
        const float* qrow = query + (size_t)b * D;
        const float* wrow = Wq + (size_t)d * D;
        float s = 0.f;
        #pragma unroll
        for (int i = 0; i < D / 64; ++i) s += qrow[lane + i * 64] * wrow[lane + i * 64];
        #pragma unroll
        for (int off = 32; off > 0; off >>= 1) s += __shfl_down(s, off, 64);
        if (lane == 0) qout[(size_t)b * D + d] = s;
    } else if (gb < 16384) {
        // ---- Amem conv-ext tail ----
        const int idx = (gb - 12288) * 256 + threadIdx.x;
        const int row = idx >> 4;          // b*T + t
        const int j0 = (idx & 15) * 4;
        const int b = row >> 11;
        const int t = row & (T - 1);
        bf16_4 o;
        #pragma unroll
        for (int u = 0; u < 4; ++u) {
            const int jj = j0 + u;
            float val = 0.f;
            if (jj < KEXT) {
                const int c = (jj >= KW) ? 1 : 0;
                const int kp = jj - c * KW;
                const int ts = t + kp - CPAD;
                if (ts >= 0 && ts < T)
                    val = (c ? cum : prev)[(size_t)b * T + ts];
            }
            o[u] = (__bf16)val;
        }
        *(bf16_4*)(Amem + (size_t)row * KTOT + D + j0) = o;
    } else {
        // ---- Bext = bf16([Wm | Wloc]) ----
        const int idx = (gb - 16384) * 256 + threadIdx.x;
        const int d = idx / (KTOT / 4);
        const int kk = (idx % (KTOT / 4)) * 4;
        bf16_4 o;
        #pragma unroll
        for (int u = 0; u < 4; ++u) {
            const int k = kk + u;
            float val = 0.f;
            if (k < D) val = Wm[(size_t)d * D + k];
            else {
                const int jj = k - D;
                if (jj < KEXT) {
                    const int c = (jj >= KW) ? 1 : 0;
                    const int kp = jj - c * KW;
                    val = Wloc[((size_t)d * 2 + c) * KW + kp];
                }
            }
            o[u] = (__bf16)val;
        }
        *(bf16_4*)(Bext + (size_t)d * KTOT + kk) = o;
    }
}

// ---------------- K2: 256x256 phase-split MFMA GEMM + tanh*v epilogue ----------------
// m201-template port (T3+T4+T5): per K-tile (BK=64) 4 quadrant-phases, each
// {ds-read this phase's frags; issue 1 half-tile glds(k+1); BAR; 16 MFMA under
// setprio; counted vmcnt gate; BAR}. Never vmcnt(0) in the loop.
// Epilogue: per-t e partials reduced across the 4 wn-waves in LDS (reusing As
// after VM0+BAR), written as e_part[B,T,4] (one column per blockIdx.y).
__global__ __launch_bounds__(512, 2) void k_gemm_e(
    const __bf16* __restrict__ Amem, const __bf16* __restrict__ Bext,
    const float* __restrict__ qv, const float* __restrict__ vvec,
    float* __restrict__ e_part) {
    __shared__ bf16_8 As[2][2048];   // 2 x 32 KB  (32 slots x 64 lanes)
    __shared__ bf16_8 Bs[2][2048];   // 2 x 32 KB  -> 128 KB total

    const int t0 = blockIdx.x * BM;
    const int d0 = blockIdx.y * BN;
    const int b  = blockIdx.z;
    const int tid  = threadIdx.x;
    const int lane = tid & 63;
    const int w    = tid >> 6;     // 0..7
    const int wm   = w >> 2;       // 0..1  (row-wave)
    const int wn   = w & 3;        // 0..3  (col-wave)
    const int ml   = lane & 15;
    const int qk   = lane >> 4;

    f32x4 acc[8][4] = {};

    const __bf16* gA[2][2];
    const __bf16* gB[2][2];
    int sA[2][2], sB[2][2];
    #pragma unroll
    for (int h = 0; h < 2; ++h) {
        #pragma unroll
        for (int j = 0; j < 2; ++j) {
            const int idx = j * 8 + w;
            const int p = idx >> 1, kfa = idx & 1;
            const int mf = h * 4 + (p & 3) + (idx & 8);
            const int nf = h * 2 + (p & 1) + (p >> 1) * 4;
            gA[h][j] = Amem + ((size_t)b * T + t0 + mf * 16 + ml) * KTOT + kfa * 32 + qk * 8;
            sA[h][j] = (mf * 2 + kfa) * 64;
            gB[h][j] = Bext + (size_t)(d0 + nf * 16 + ml) * KTOT + kfa * 32 + qk * 8;
            sB[h][j] = (nf * 2 + kfa) * 64;
        }
    }

    bf16_8 areg[4][2];               // current A quadrant (overwritten at ph2)
    bf16_8 breg0[2][2], breg1[2][2]; // B halves jh=0 / jh=1

    auto STG_A = [&](int h, int kcol, bf16_8* dst) {
        glds16(gA[h][0] + kcol, dst + sA[h][0]);
        glds16(gA[h][1] + kcol, dst + sA[h][1]);
    };
    auto STG_B = [&](int h, int kcol, bf16_8* dst) {
        glds16(gB[h][0] + kcol, dst + sB[h][0]);
        glds16(gB[h][1] + kcol, dst + sB[h][1]);
    };
    auto LDA = [&](const bf16_8* buf, int ih) {
        #pragma unroll
        for (int i = 0; i < 4; ++i)
            #pragma unroll
            for (int kf = 0; kf < 2; ++kf)
                areg[i][kf] = buf[((wm * 8 + ih * 4 + i) * 2 + kf) * 64 + lane];
    };
    auto LDB = [&](bf16_8 (&dst)[2][2], const bf16_8* buf, int jh) {
        #pragma unroll
        for (int j = 0; j < 2; ++j)
            #pragma unroll
            for (int kf = 0; kf < 2; ++kf)
                dst[j][kf] = buf[((wn * 4 + jh * 2 + j) * 2 + kf) * 64 + lane];
    };
    auto QMM = [&](bf16_8 (&bb)[2][2], int ih, int jh) {
        #pragma unroll
        for (int i = 0; i < 4; ++i)
            #pragma unroll
            for (int kf = 0; kf < 2; ++kf)
                #pragma unroll
                for (int j = 0; j < 2; ++j)
                    acc[ih * 4 + i][jh * 2 + j] = __builtin_amdgcn_mfma_f32_16x16x32_bf16(
                        areg[i][kf], bb[j][kf], acc[ih * 4 + i][jh * 2 + j], 0, 0, 0);
    };

    // ---- prologue: stage tile 0, FIFO order Ah0,Bh0,Bh1,Ah1 (8 loads) ----
    STG_A(0, 0, As[0]);
    STG_B(0, 0, Bs[0]);
    STG_B(1, 0, Bs[0]);
    STG_A(1, 0, As[0]);
    VM4;                 // drains Ah0(0),Bh0(0); leaves Bh1(0),Ah1(0) in flight
    BAR;

    #pragma unroll 1
    for (int k = 0; k < NK; ++k) {
        const bf16_8* Ac = As[k & 1];
        const bf16_8* Bc = Bs[k & 1];
        bf16_8* An = As[(k + 1) & 1];
        bf16_8* Bn = Bs[(k + 1) & 1];
        const int c1 = ((k + 1 < NK) ? (k + 1) : 0) * KSTEP;   // dead-wrap tail
        // ph0: quad(0,0). reads Ah0(k),Bh0(k) [drained end of tile k-1]
        LDA(Ac, 0);
        LDB(breg0, Bc, 0);
        STG_A(0, c1, An);            // outstanding: Bh1(k),Ah1(k),Ah0(k+1) = 6
        BAR;
        PRIO1; QMM(breg0, 0, 0); PRIO0;
        VM4;                         // drains Bh1(k)  [needed ph1]
        BAR;
        // ph1: quad(0,1). reads Bh1(k)
        LDB(breg1, Bc, 1);
        STG_B(0, c1, Bn);            // outstanding: Ah1(k),Ah0(k+1),Bh0(k+1) = 6
        BAR;
        PRIO1; QMM(breg1, 0, 1); PRIO0;
        VM4;                         // drains Ah1(k)  [needed ph2]
        BAR;
        // ph2: quad(1,0). reads Ah1(k)
        LDA(Ac, 1);
        STG_B(1, c1, Bn);            // outstanding: Ah0(k+1),Bh0(k+1),Bh1(k+1) = 6
        BAR;
        PRIO1; QMM(breg0, 1, 0); PRIO0;
        BAR;                         // no gate (ph3 reads nothing)
        // ph3: quad(1,1). no reads
        STG_A(1, c1, An);            // outstanding: 8
        BAR;
        PRIO1; QMM(breg1, 1, 1); PRIO0;
        VM4;                         // drains Ah0(k+1),Bh0(k+1) [needed next ph0]
        BAR;
    }
    VM0;   // drain dead-wrap loads (they target As[1]/Bs[1])
    BAR;   // all waves' dead-wrap writes landed; all LDS reads done

    // ---- epilogue: e(t) = sum_d tanh(acc + q[d]) * v[d], reduced over wn ----
    float qreg[4], vreg[4];
    #pragma unroll
    for (int jb = 0; jb < 4; ++jb) {
        const int d = d0 + wn * 64 + jb * 16 + ml;
        qreg[jb] = qv[(size_t)b * D + d];
        vreg[jb] = vvec[d];
    }
    float (*est)[256] = (float (*)[256])(&As[0][0]);   // 4 KB of As[0] (not dead-wrap target)
    #pragma unroll
    for (int ia = 0; ia < 8; ++ia) {
        #pragma unroll
        for (int r = 0; r < 4; ++r) {
            float s = 0.f;
            #pragma unroll
            for (int jb = 0; jb < 4; ++jb)
                s += tanh_fast(acc[ia][jb][r] + qreg[jb]) * vreg[jb];
            #pragma unroll
            for (int off = 8; off > 0; off >>= 1)
                s += __shfl_down(s, off, 16);
            if (ml == 0)
                est[wn][wm * 128 + ia * 16 + qk * 4 + r] = s;
        }
    }
    __syncthreads();
    if (tid < 256) {
        const float e = est[0][tid] + est[1][tid] + est[2][tid] + est[3][tid];
        e_part[((size_t)b * T + t0 + tid) * 4 + blockIdx.y] = e;
    }
}

// ---------------- K3: masked softmax over T (e_part [B,T,4]) ----------------
__global__ __launch_bounds__(256) void k_softmax(const float* __restrict__ e_part,
                                                 const int* __restrict__ mask,
                                                 float* __restrict__ aout) {
    const int b = blockIdx.x;
    const int tid = threadIdx.x;
    __shared__ float red[256];
    float ev[8];
    float lmax = -INFINITY;
    #pragma unroll
    for (int i = 0; i < 8; ++i) {
        const int t = tid + i * 256;
        const f32x4 p4 = *(const f32x4*)(e_part + ((size_t)b * T + t) * 4);
        float s = p4[0] + p4[1] + p4[2] + p4[3];
        if (mask[(size_t)b * T + t] != 0) s = -INFINITY;
        ev[i] = s;
        lmax = fmaxf(lmax, s);
    }
    red[tid] = lmax; __syncthreads();
    for (int off = 128; off > 0; off >>= 1) {
        if (tid < off) red[tid] = fmaxf(red[tid], red[tid + off]);
        __syncthreads();
    }
    const float mx = red[0]; __syncthreads();
    float lsum = 0.f;
    #pragma unroll
    for (int i = 0; i < 8; ++i) {
        const float x = expf(ev[i] - mx);
        ev[i] = x;
        lsum += x;
    }
    red[tid] = lsum; __syncthreads();
    for (int off = 128; off > 0; off >>= 1) {
        if (tid < off) red[tid] += red[tid + off];
        __syncthreads();
    }
    const float inv = 1.f / red[0];
    #pragma unroll
    for (int i = 0; i < 8; ++i)
        aout[(size_t)b * T + tid + i * 256] = ev[i] * inv;
}

// ---------------- K4: partial ctx from bf16 Amem (L3-resident) ----------------
__global__ __launch_bounds__(256) void k_ctx_part(const __bf16* __restrict__ Amem,
                                                  const float* __restrict__ a,
                                                  float* __restrict__ ctx_part) {
    const int b = blockIdx.x;
    const int tc = blockIdx.y;       // 0..31, 64 t each
    const int d4 = threadIdx.x * 4;
    f32x4 acc = {0.f, 0.f, 0.f, 0.f};
    const __bf16* mb = Amem + ((size_t)b * T + (size_t)tc * 64) * KTOT + d4;
    const float* ab = a + (size_t)b * T + (size_t)tc * 64;
    #pragma unroll 4
    for (int t = 0; t < 64; ++t) {
        const float wgt = ab[t];
        const bf16_4 m4 = *(const bf16_4*)(mb + (size_t)t * KTOT);
        #pragma unroll
        for (int u = 0; u < 4; ++u) acc[u] += wgt * (float)m4[u];
    }
    *(f32x4*)(ctx_part + ((size_t)(b * 32 + tc)) * D + d4) = acc;
}

// ---------------- K5: reduce 32 ctx partials ----------------
__global__ __launch_bounds__(256) void k_ctx_red(const float* __restrict__ ctx_part,
                                                 float* __restrict__ ctx) {
    const int idx = blockIdx.x * 256 + threadIdx.x;
    const int b = idx >> 10, d = idx & 1023;
    float s = 0.f;
    #pragma unroll
    for (int tc = 0; tc < 32; ++tc) s += ctx_part[((size_t)(b * 32 + tc)) * D + d];
    ctx[idx] = s;
}

extern "C" void kernel_launch(void* const* d_in, const int* in_sizes, int n_in,
                              void* d_out, int out_size, void* d_ws, size_t ws_size,
                              hipStream_t stream) {
    const float* query  = (const float*)d_in[0];
    const float* memory = (const float*)d_in[1];
    const float* prev   = (const float*)d_in[2];
    const float* cum    = (const float*)d_in[3];
    const int*   mask   = (const int*)d_in[4];
    const float* Wq     = (const float*)d_in[5];
    const float* Wm     = (const float*)d_in[6];
    const float* Wloc   = (const float*)d_in[7];
    const float* v      = (const float*)d_in[8];

    float* out = (float*)d_out;
    float* ctx = out;               // [B, D]
    float* a   = out + BATCH * D;   // [B, T]

    char* ws = (char*)d_ws;
    float*  qv       = (float*)(ws + 0);                 // 128 KB
    float*  e_part   = (float*)(ws + 131072);            // 1 MB   [B,T,4]
    float*  ctx_part = (float*)(ws + 4325376);           // 4 MB   [B,32,D]
    __bf16* Bext     = (__bf16*)(ws + 8519680);          // 2.23 MB [1024,1088]
    __bf16* Amem     = (__bf16*)(ws + 10747904);         // 136 MB  [B*T,1088] bf16
    // total ~146.3 MB

    k_prep_all<<<PREP_BLOCKS, 256, 0, stream>>>(Wm, Wloc, Bext, memory, Amem,
                                                prev, cum, query, Wq, qv);
    k_gemm_e<<<dim3(T / BM, D / BN, BATCH), 512, 0, stream>>>(Amem, Bext, qv, v, e_part);
    k_softmax<<<BATCH, 256, 0, stream>>>(e_part, mask, a);
    k_ctx_part<<<dim3(BATCH, 32), 256, 0, stream>>>(Amem, a, ctx_part);
    k_ctx_red<<<(BATCH * D) / 256, 256, 0, stream>>>(ctx_part, ctx);
}

// Round 6
// 618.060 us; speedup vs baseline: 1.2248x; 1.0371x over previous
//
#include <hip/hip_runtime.h>
#include <math.h>

#define BATCH 32
#define T 2048
#define D 1024
#define KW 31
#define CPAD 15
#define KEXT 62      // 2*31 conv-patch columns
#define KTOT 1088    // 1024 + 64 (ext cols live in Amem/Bext tail)
#define BM 256
#define BN 256
#define KSTEP 64
#define NK (KTOT / KSTEP)   // 17

typedef __bf16 bf16_8 __attribute__((ext_vector_type(8)));
typedef __bf16 bf16_4 __attribute__((ext_vector_type(4)));
typedef float  f32x4  __attribute__((ext_vector_type(4)));

__device__ __forceinline__ float tanh_fast(float x) {
    return 1.f - 2.f * __builtin_amdgcn_rcpf(__expf(2.f * x) + 1.f);
}

__device__ __forceinline__ void glds16(const void* gsrc, void* ldst) {
    __builtin_amdgcn_global_load_lds(
        (const __attribute__((address_space(1))) unsigned int*)gsrc,
        (__attribute__((address_space(3))) unsigned int*)ldst, 16, 0, 0);
}

#define VM6 asm volatile("s_waitcnt vmcnt(6)" ::: "memory")
#define VM4 asm volatile("s_waitcnt vmcnt(4)" ::: "memory")
#define VM0 asm volatile("s_waitcnt vmcnt(0)" ::: "memory")
#define BAR __builtin_amdgcn_s_barrier()
#define PRIO1 __builtin_amdgcn_s_setprio(1)
#define PRIO0 __builtin_amdgcn_s_setprio(0)

// ---------------- P: merged prep (amem | q | aloc | b) ----------------
//   [0,4096)        : Amem[row][0:1024] = bf16(memory)
//   [4096,12288)    : qv = query @ Wq^T
//   [12288,16384)   : Amem[row][1024:1088] = bf16 conv patches
//   [16384,17472)   : Bext = bf16([Wm | Wloc])
#define PREP_BLOCKS 17472
__global__ __launch_bounds__(256) void k_prep_all(
    const float* __restrict__ Wm, const float* __restrict__ Wloc,
    __bf16* __restrict__ Bext,
    const float* __restrict__ memory, __bf16* __restrict__ Amem,
    const float* __restrict__ prev, const float* __restrict__ cum,
    const float* __restrict__ query, const float* __restrict__ Wq,
    float* __restrict__ qout) {
    const int gb = blockIdx.x;
    if (gb < 4096) {
        // ---- Amem body: 16 fp32 -> bf16 per thread, grid-stride ----
        const int nvec = BATCH * T * (D / 16);
        for (int idx = gb * 256 + threadIdx.x; idx < nvec; idx += 4096 * 256) {
            const int row = idx >> 6;              // b*T + t  (64 threads/row)
            const int c = (idx & 63) * 16;
            const float* src = memory + (size_t)row * D + c;
            const f32x4 a0 = *(const f32x4*)(src);
            const f32x4 a1 = *(const f32x4*)(src + 4);
            const f32x4 a2 = *(const f32x4*)(src + 8);
            const f32x4 a3 = *(const f32x4*)(src + 12);
            bf16_8 o0, o1;
            #pragma unroll
            for (int u = 0; u < 4; ++u) {
                o0[u] = (__bf16)a0[u]; o0[u + 4] = (__bf16)a1[u];
                o1[u] = (__bf16)a2[u]; o1[u + 4] = (__bf16)a3[u];
            }
            __bf16* dst = Amem + (size_t)row * KTOT + c;
            *(bf16_8*)(dst) = o0;
            *(bf16_8*)(dst + 8) = o1;
        }
    } else if (gb < 12288) {
        // ---- q = query @ Wq^T ----
        const int j = gb - 4096;
        const int xb = j & 255;
        const int b = j >> 8;
        const int w = threadIdx.x >> 6;
        const int lane = threadIdx.x & 63;
        const int d = xb * 4 + w;
        const float* qrow = query + (size_t)b * D;
        const float* wrow = Wq + (size_t)d * D;
        float s = 0.f;
        #pragma unroll
        for (int i = 0; i < D / 64; ++i) s += qrow[lane + i * 64] * wrow[lane + i * 64];
        #pragma unroll
        for (int off = 32; off > 0; off >>= 1) s += __shfl_down(s, off, 64);
        if (lane == 0) qout[(size_t)b * D + d] = s;
    } else if (gb < 16384) {
        // ---- Amem conv-ext tail ----
        const int idx = (gb - 12288) * 256 + threadIdx.x;
        const int row = idx >> 4;          // b*T + t
        const int j0 = (idx & 15) * 4;
        const int b = row >> 11;
        const int t = row & (T - 1);
        bf16_4 o;
        #pragma unroll
        for (int u = 0; u < 4; ++u) {
            const int jj = j0 + u;
            float val = 0.f;
            if (jj < KEXT) {
                const int c = (jj >= KW) ? 1 : 0;
                const int kp = jj - c * KW;
                const int ts = t + kp - CPAD;
                if (ts >= 0 && ts < T)
                    val = (c ? cum : prev)[(size_t)b * T + ts];
            }
            o[u] = (__bf16)val;
        }
        *(bf16_4*)(Amem + (size_t)row * KTOT + D + j0) = o;
    } else {
        // ---- Bext = bf16([Wm | Wloc]) ----
        const int idx = (gb - 16384) * 256 + threadIdx.x;
        const int d = idx / (KTOT / 4);
        const int kk = (idx % (KTOT / 4)) * 4;
        bf16_4 o;
        #pragma unroll
        for (int u = 0; u < 4; ++u) {
            const int k = kk + u;
            float val = 0.f;
            if (k < D) val = Wm[(size_t)d * D + k];
            else {
                const int jj = k - D;
                if (jj < KEXT) {
                    const int c = (jj >= KW) ? 1 : 0;
                    const int kp = jj - c * KW;
                    val = Wloc[((size_t)d * 2 + c) * KW + kp];
                }
            }
            o[u] = (__bf16)val;
        }
        *(bf16_4*)(Bext + (size_t)d * KTOT + kk) = o;
    }
}

// ---------------- K2: 256x256 phase-split MFMA GEMM + tanh*v epilogue ----------------
// Re-timed staging (3-phase latency cover per half-tile): issue Ah0+Bh0 at ph0,
// Bh1 at ph1, Ah1 at ph2; gates vmcnt(6)@ph0, vmcnt(6)@ph1, vmcnt(4)@ph3 —
// every half-tile has ~3 phases in flight before its drain; never below 4
// outstanding in the loop. Double-buffer by K-tile so STG never collides with
// current-tile reads. Epilogue reduces the 4 wn-waves' e partials in LDS.
__global__ __launch_bounds__(512, 2) void k_gemm_e(
    const __bf16* __restrict__ Amem, const __bf16* __restrict__ Bext,
    const float* __restrict__ qv, const float* __restrict__ vvec,
    float* __restrict__ e_part) {
    __shared__ bf16_8 As[2][2048];   // 2 x 32 KB  (32 slots x 64 lanes)
    __shared__ bf16_8 Bs[2][2048];   // 2 x 32 KB  -> 128 KB total

    const int t0 = blockIdx.x * BM;
    const int d0 = blockIdx.y * BN;
    const int b  = blockIdx.z;
    const int tid  = threadIdx.x;
    const int lane = tid & 63;
    const int w    = tid >> 6;     // 0..7
    const int wm   = w >> 2;       // 0..1  (row-wave)
    const int wn   = w & 3;        // 0..3  (col-wave)
    const int ml   = lane & 15;
    const int qk   = lane >> 4;

    f32x4 acc[8][4] = {};

    const __bf16* gA[2][2];
    const __bf16* gB[2][2];
    int sA[2][2], sB[2][2];
    #pragma unroll
    for (int h = 0; h < 2; ++h) {
        #pragma unroll
        for (int j = 0; j < 2; ++j) {
            const int idx = j * 8 + w;
            const int p = idx >> 1, kfa = idx & 1;
            const int mf = h * 4 + (p & 3) + (idx & 8);
            const int nf = h * 2 + (p & 1) + (p >> 1) * 4;
            gA[h][j] = Amem + ((size_t)b * T + t0 + mf * 16 + ml) * KTOT + kfa * 32 + qk * 8;
            sA[h][j] = (mf * 2 + kfa) * 64;
            gB[h][j] = Bext + (size_t)(d0 + nf * 16 + ml) * KTOT + kfa * 32 + qk * 8;
            sB[h][j] = (nf * 2 + kfa) * 64;
        }
    }

    bf16_8 areg[4][2];               // current A quadrant (overwritten at ph2)
    bf16_8 breg0[2][2], breg1[2][2]; // B halves jh=0 / jh=1

    auto STG_A = [&](int h, int kcol, bf16_8* dst) {
        glds16(gA[h][0] + kcol, dst + sA[h][0]);
        glds16(gA[h][1] + kcol, dst + sA[h][1]);
    };
    auto STG_B = [&](int h, int kcol, bf16_8* dst) {
        glds16(gB[h][0] + kcol, dst + sB[h][0]);
        glds16(gB[h][1] + kcol, dst + sB[h][1]);
    };
    auto LDA = [&](const bf16_8* buf, int ih) {
        #pragma unroll
        for (int i = 0; i < 4; ++i)
            #pragma unroll
            for (int kf = 0; kf < 2; ++kf)
                areg[i][kf] = buf[((wm * 8 + ih * 4 + i) * 2 + kf) * 64 + lane];
    };
    auto LDB = [&](bf16_8 (&dst)[2][2], const bf16_8* buf, int jh) {
        #pragma unroll
        for (int j = 0; j < 2; ++j)
            #pragma unroll
            for (int kf = 0; kf < 2; ++kf)
                dst[j][kf] = buf[((wn * 4 + jh * 2 + j) * 2 + kf) * 64 + lane];
    };
    auto QMM = [&](bf16_8 (&bb)[2][2], int ih, int jh) {
        #pragma unroll
        for (int i = 0; i < 4; ++i)
            #pragma unroll
            for (int kf = 0; kf < 2; ++kf)
                #pragma unroll
                for (int j = 0; j < 2; ++j)
                    acc[ih * 4 + i][jh * 2 + j] = __builtin_amdgcn_mfma_f32_16x16x32_bf16(
                        areg[i][kf], bb[j][kf], acc[ih * 4 + i][jh * 2 + j], 0, 0, 0);
    };

    // ---- prologue: stage tile 0, FIFO order Ah0,Bh0,Bh1,Ah1 (8 loads) ----
    STG_A(0, 0, As[0]);
    STG_B(0, 0, Bs[0]);
    STG_B(1, 0, Bs[0]);
    STG_A(1, 0, As[0]);
    VM4;                 // drains Ah0(0),Bh0(0); leaves Bh1(0),Ah1(0) in flight
    BAR;

    #pragma unroll 1
    for (int k = 0; k < NK; ++k) {
        const bf16_8* Ac = As[k & 1];
        const bf16_8* Bc = Bs[k & 1];
        bf16_8* An = As[(k + 1) & 1];
        bf16_8* Bn = Bs[(k + 1) & 1];
        const int c1 = ((k + 1 < NK) ? (k + 1) : 0) * KSTEP;   // dead-wrap tail
        // ph0: quad(0,0). reads Ah0(k),Bh0(k) [drained end of tile k-1]
        LDA(Ac, 0);
        LDB(breg0, Bc, 0);
        STG_A(0, c1, An);            // issue both ph0 halves of k+1 (3.5-ph cover)
        STG_B(0, c1, Bn);
        BAR;
        PRIO1; QMM(breg0, 0, 0); PRIO0;
        VM6;                         // drains Bh1(k)  [issued ph1 of k-1, 3-ph cover]
        BAR;
        // ph1: quad(0,1). reads Bh1(k)
        LDB(breg1, Bc, 1);
        STG_B(1, c1, Bn);
        BAR;
        PRIO1; QMM(breg1, 0, 1); PRIO0;
        VM6;                         // drains Ah1(k)  [issued ph2 of k-1, 3-ph cover]
        BAR;
        // ph2: quad(1,0). reads Ah1(k)
        LDA(Ac, 1);
        STG_A(1, c1, An);
        BAR;
        PRIO1; QMM(breg0, 1, 0); PRIO0;
        BAR;                         // no gate (ph3 reads no LDS)
        // ph3: quad(1,1). pure registers
        PRIO1; QMM(breg1, 1, 1); PRIO0;
        VM4;                         // drains Ah0(k+1),Bh0(k+1) [3.5-ph cover]
        BAR;
    }
    VM0;   // drain dead-wrap loads (they target As[1]/Bs[1])
    BAR;   // all waves' dead-wrap writes landed; all LDS reads done

    // ---- epilogue: e(t) = sum_d tanh(acc + q[d]) * v[d], reduced over wn ----
    float qreg[4], vreg[4];
    #pragma unroll
    for (int jb = 0; jb < 4; ++jb) {
        const int d = d0 + wn * 64 + jb * 16 + ml;
        qreg[jb] = qv[(size_t)b * D + d];
        vreg[jb] = vvec[d];
    }
    float (*est)[256] = (float (*)[256])(&As[0][0]);   // 4 KB of As[0] (not dead-wrap target)
    #pragma unroll
    for (int ia = 0; ia < 8; ++ia) {
        #pragma unroll
        for (int r = 0; r < 4; ++r) {
            float s = 0.f;
            #pragma unroll
            for (int jb = 0; jb < 4; ++jb)
                s += tanh_fast(acc[ia][jb][r] + qreg[jb]) * vreg[jb];
            #pragma unroll
            for (int off = 8; off > 0; off >>= 1)
                s += __shfl_down(s, off, 16);
            if (ml == 0)
                est[wn][wm * 128 + ia * 16 + qk * 4 + r] = s;
        }
    }
    __syncthreads();
    if (tid < 256) {
        const float e = est[0][tid] + est[1][tid] + est[2][tid] + est[3][tid];
        e_part[((size_t)b * T + t0 + tid) * 4 + blockIdx.y] = e;
    }
}

// ---------------- K3: masked softmax over T (e_part [B,T,4]) ----------------
__global__ __launch_bounds__(256) void k_softmax(const float* __restrict__ e_part,
                                                 const int* __restrict__ mask,
                                                 float* __restrict__ aout) {
    const int b = blockIdx.x;
    const int tid = threadIdx.x;
    __shared__ float red[256];
    float ev[8];
    float lmax = -INFINITY;
    #pragma unroll
    for (int i = 0; i < 8; ++i) {
        const int t = tid + i * 256;
        const f32x4 p4 = *(const f32x4*)(e_part + ((size_t)b * T + t) * 4);
        float s = p4[0] + p4[1] + p4[2] + p4[3];
        if (mask[(size_t)b * T + t] != 0) s = -INFINITY;
        ev[i] = s;
        lmax = fmaxf(lmax, s);
    }
    red[tid] = lmax; __syncthreads();
    for (int off = 128; off > 0; off >>= 1) {
        if (tid < off) red[tid] = fmaxf(red[tid], red[tid + off]);
        __syncthreads();
    }
    const float mx = red[0]; __syncthreads();
    float lsum = 0.f;
    #pragma unroll
    for (int i = 0; i < 8; ++i) {
        const float x = expf(ev[i] - mx);
        ev[i] = x;
        lsum += x;
    }
    red[tid] = lsum; __syncthreads();
    for (int off = 128; off > 0; off >>= 1) {
        if (tid < off) red[tid] += red[tid + off];
        __syncthreads();
    }
    const float inv = 1.f / red[0];
    #pragma unroll
    for (int i = 0; i < 8; ++i)
        aout[(size_t)b * T + tid + i * 256] = ev[i] * inv;
}

// ---------------- K4: partial ctx from bf16 Amem, 16B loads, 2-way t-split ----------------
__global__ __launch_bounds__(256) void k_ctx_part(const __bf16* __restrict__ Amem,
                                                  const float* __restrict__ a,
                                                  float* __restrict__ ctx_part) {
    const int b = blockIdx.x;
    const int tc = blockIdx.y;           // 0..31, 64 t each
    const int th = threadIdx.x >> 7;     // t-half 0/1 (32 t each)
    const int cg = threadIdx.x & 127;    // col group
    const int d8 = cg * 8;
    __shared__ float red[128][8];
    float acc[8] = {};
    const int trow = tc * 64 + th * 32;
    const __bf16* mb = Amem + ((size_t)b * T + trow) * KTOT + d8;
    const float* ab = a + (size_t)b * T + trow;
    #pragma unroll 4
    for (int t = 0; t < 32; ++t) {
        const float wgt = ab[t];
        const bf16_8 m8 = *(const bf16_8*)(mb + (size_t)t * KTOT);
        #pragma unroll
        for (int u = 0; u < 8; ++u) acc[u] += wgt * (float)m8[u];
    }
    if (th == 1) {
        #pragma unroll
        for (int u = 0; u < 8; ++u) red[cg][u] = acc[u];
    }
    __syncthreads();
    if (th == 0) {
        f32x4 o0, o1;
        #pragma unroll
        for (int u = 0; u < 4; ++u) {
            o0[u] = acc[u] + red[cg][u];
            o1[u] = acc[u + 4] + red[cg][u + 4];
        }
        float* dst = ctx_part + ((size_t)(b * 32 + tc)) * D + d8;
        *(f32x4*)(dst) = o0;
        *(f32x4*)(dst + 4) = o1;
    }
}

// ---------------- K5: reduce 32 ctx partials ----------------
__global__ __launch_bounds__(256) void k_ctx_red(const float* __restrict__ ctx_part,
                                                 float* __restrict__ ctx) {
    const int idx = blockIdx.x * 256 + threadIdx.x;
    const int b = idx >> 10, d = idx & 1023;
    float s = 0.f;
    #pragma unroll
    for (int tc = 0; tc < 32; ++tc) s += ctx_part[((size_t)(b * 32 + tc)) * D + d];
    ctx[idx] = s;
}

extern "C" void kernel_launch(void* const* d_in, const int* in_sizes, int n_in,
                              void* d_out, int out_size, void* d_ws, size_t ws_size,
                              hipStream_t stream) {
    const float* query  = (const float*)d_in[0];
    const float* memory = (const float*)d_in[1];
    const float* prev   = (const float*)d_in[2];
    const float* cum    = (const float*)d_in[3];
    const int*   mask   = (const int*)d_in[4];
    const float* Wq     = (const float*)d_in[5];
    const float* Wm     = (const float*)d_in[6];
    const float* Wloc   = (const float*)d_in[7];
    const float* v      = (const float*)d_in[8];

    float* out = (float*)d_out;
    float* ctx = out;               // [B, D]
    float* a   = out + BATCH * D;   // [B, T]

    char* ws = (char*)d_ws;
    float*  qv       = (float*)(ws + 0);                 // 128 KB
    float*  e_part   = (float*)(ws + 131072);            // 1 MB   [B,T,4]
    float*  ctx_part = (float*)(ws + 4325376);           // 4 MB   [B,32,D]
    __bf16* Bext     = (__bf16*)(ws + 8519680);          // 2.23 MB [1024,1088]
    __bf16* Amem     = (__bf16*)(ws + 10747904);         // 136 MB  [B*T,1088] bf16
    // total ~146.3 MB

    k_prep_all<<<PREP_BLOCKS, 256, 0, stream>>>(Wm, Wloc, Bext, memory, Amem,
                                                prev, cum, query, Wq, qv);
    k_gemm_e<<<dim3(T / BM, D / BN, BATCH), 512, 0, stream>>>(Amem, Bext, qv, v, e_part);
    k_softmax<<<BATCH, 256, 0, stream>>>(e_part, mask, a);
    k_ctx_part<<<dim3(BATCH, 32), 256, 0, stream>>>(Amem, a, ctx_part);
    k_ctx_red<<<(BATCH * D) / 256, 256, 0, stream>>>(ctx_part, ctx);
}